// Round 5
// baseline (5505.468 us; speedup 1.0000x reference)
//
#include <hip/hip_runtime.h>
#include <hip/hip_cooperative_groups.h>

namespace cg = cooperative_groups;

#define NN 50000
#define NE 800000
#define CIN 128
#define HH 64
#define NCLS 40
#define NL 15
#define DTC 0.1f
#define LNEPS 1e-5f
#define NB_SCAN 196   // ceil(50000/256)
#define COOP_BLOCKS 1024

typedef float f32x2 __attribute__((ext_vector_type(2)));

// ---------------- bf16x2 / fp8x2 pack-unpack ----------------

__device__ inline unsigned pack_bf2(float x, float y) {
    unsigned ux = __float_as_uint(x);
    unsigned uy = __float_as_uint(y);
    ux = (ux + 0x7fffu + ((ux >> 16) & 1u)) >> 16;   // RNE
    uy = (uy + 0x7fffu + ((uy >> 16) & 1u)) >> 16;
    return ux | (uy << 16);
}
__device__ inline float2 unpack_bf2(unsigned p) {
    float2 r;
    r.x = __uint_as_float(p << 16);
    r.y = __uint_as_float(p & 0xffff0000u);
    return r;
}
__device__ inline unsigned short pack_fp8x2(float x, float y) {
    int r = __builtin_amdgcn_cvt_pk_fp8_f32(x, y, 0, false);
    return (unsigned short)(r & 0xffff);
}
__device__ inline float2 unpack_fp8x2(unsigned short p) {
    f32x2 v = __builtin_amdgcn_cvt_pk_f32_fp8((int)(unsigned)p, false);
    float2 r; r.x = v.x; r.y = v.y; return r;
}

// ---------------- degree / normalization precompute ----------------

__global__ __launch_bounds__(256) void k_deg(const int* __restrict__ dst, int* __restrict__ deg) {
    int e = blockIdx.x * 256 + threadIdx.x;
    if (e < NE) atomicAdd(&deg[dst[e]], 1);
}

__global__ __launch_bounds__(256) void k_scan1(const int* __restrict__ deg, int* __restrict__ rp,
                                               int* __restrict__ bsum, float* __restrict__ dinv) {
    int i = blockIdx.x * 256 + threadIdx.x;
    int v = (i < NN) ? deg[i] : 0;
    if (i < NN) dinv[i] = rsqrtf(fmaxf((float)v, 1.0f));
    int lane = threadIdx.x & 63, wid = threadIdx.x >> 6;
    int inc = v;
#pragma unroll
    for (int d = 1; d < 64; d <<= 1) {
        int t = __shfl_up(inc, d, 64);
        if (lane >= d) inc += t;
    }
    __shared__ int wsum[4];
    if (lane == 63) wsum[wid] = inc;
    __syncthreads();
    int woff = 0;
#pragma unroll
    for (int w = 0; w < 4; ++w)
        if (w < wid) woff += wsum[w];
    if (i < NN) rp[i] = woff + inc - v;
    if (threadIdx.x == 255) bsum[blockIdx.x] = woff + inc;
}

__global__ __launch_bounds__(256) void k_scan2(const int* __restrict__ bsum, int* __restrict__ boff) {
    int t = threadIdx.x;
    int v = (t < NB_SCAN) ? bsum[t] : 0;
    int lane = t & 63, wid = t >> 6;
    int inc = v;
#pragma unroll
    for (int d = 1; d < 64; d <<= 1) {
        int tt = __shfl_up(inc, d, 64);
        if (lane >= d) inc += tt;
    }
    __shared__ int wsum[4];
    if (lane == 63) wsum[wid] = inc;
    __syncthreads();
    int woff = 0;
#pragma unroll
    for (int w = 0; w < 4; ++w)
        if (w < wid) woff += wsum[w];
    boff[t] = woff + inc - v;
}

__global__ __launch_bounds__(256) void k_scan3(int* __restrict__ rp, const int* __restrict__ boff) {
    int i = blockIdx.x * 256 + threadIdx.x;
    if (i < NN) rp[i] += boff[i >> 8];
    else if (i == NN) rp[NN] = NE;
}

__global__ __launch_bounds__(256) void k_scatter(const int* __restrict__ src, const int* __restrict__ dst,
                                                 const float* __restrict__ dinv, const int* __restrict__ rp,
                                                 int* __restrict__ cnt, uint2* __restrict__ edges) {
    int e = blockIdx.x * 256 + threadIdx.x;
    if (e >= NE) return;
    int s = src[e], d = dst[e];
    int pos = rp[d] + atomicAdd(&cnt[d], 1);
    uint2 rec;
    rec.x = (unsigned)s;
    rec.y = __float_as_uint(dinv[s] * dinv[d]);
    edges[pos] = rec;
}

// ---------------- lift: h = [tanh(x @ lift_w^T + b), ones]; writes layer-0 z0 ----

#define LIFT_NPB 16

__global__ __launch_bounds__(256) void k_lift(const float* __restrict__ x, const float* __restrict__ lw,
                                              const float* __restrict__ lb,
                                              const float* __restrict__ alpha, const float* __restrict__ beta,
                                              const float* __restrict__ dxp, const float* __restrict__ dyp,
                                              float* __restrict__ h, unsigned short* __restrict__ z0bf8) {
    __shared__ unsigned Wt2[CIN / 2][HH + 1];
    __shared__ float xs[LIFT_NPB][CIN];
    int t = threadIdx.x;
    for (int idx = t; idx < (CIN / 2) * HH; idx += 256) {
        int c = idx & 63, kk = idx >> 6;
        Wt2[kk][c] = pack_bf2(lw[c * CIN + 2 * kk], lw[c * CIN + 2 * kk + 1]);
    }
    int n0 = blockIdx.x * LIFT_NPB;
#pragma unroll
    for (int i = 0; i < LIFT_NPB * CIN / 256; ++i) {
        int idx = i * 256 + t;
        int r = idx >> 7, c = idx & 127;
        xs[r][c] = x[(size_t)(n0 + r) * CIN + c];
    }
    __syncthreads();
    int lane = t & 63, wid = t >> 6;
    float bias = lb[lane];
    float a = alpha[0], b = beta[0];
    float idx0 = 1.0f / (1.0f + DTC * dxp[0]);
    float idy0 = 1.0f / (1.0f + DTC * dyp[0]);
#pragma unroll
    for (int i = 0; i < 4; ++i) {
        int nl = wid * 4 + i;
        float acc0 = 0.f, acc1 = 0.f;
        const float2* xr = (const float2*)&xs[nl][0];
#pragma unroll 8
        for (int kk = 0; kk < CIN / 2; ++kk) {
            float2 xv = xr[kk];
            float2 wv = unpack_bf2(Wt2[kk][lane]);
            acc0 = fmaf(xv.x, wv.x, acc0);
            acc1 = fmaf(xv.y, wv.y, acc1);
        }
        float hx = tanhf(bias + acc0 + acc1);
        int n = n0 + nl;
        float* hr = h + (size_t)n * 128;
        hr[lane] = hx;
        hr[HH + lane] = 1.0f;
        // layer-0 z0 = rhs/diag with (X,Y)=(hx,1): xy = hx
        float rx = hx + DTC * (a * hx - b * hx);
        float ry = 1.0f + DTC * (b * hx - a);
        z0bf8[(size_t)n * HH + lane] = pack_fp8x2(rx * idx0, ry * idy0);
    }
}

// ---------------- shared phase bodies ----------------

__device__ __forceinline__ void gather_acc(const unsigned short* __restrict__ srcbuf,
                                           const uint2* __restrict__ edges,
                                           int e0, int e1, int lane, float& accX, float& accY) {
    int e = e0;
    for (; e + 8 <= e1; e += 8) {
        uint2 ed[8]; unsigned short g[8];
#pragma unroll
        for (int u = 0; u < 8; ++u) ed[u] = edges[e + u];
#pragma unroll
        for (int u = 0; u < 8; ++u) g[u] = srcbuf[(size_t)ed[u].x * HH + lane];
#pragma unroll
        for (int u = 0; u < 8; ++u) {
            float w = __uint_as_float(ed[u].y);
            float2 v = unpack_fp8x2(g[u]);
            accX = fmaf(w, v.x, accX);
            accY = fmaf(w, v.y, accY);
        }
    }
    for (; e < e1; ++e) {
        uint2 ed = edges[e];
        float w = __uint_as_float(ed.y);
        float2 v = unpack_fp8x2(srcbuf[(size_t)ed.x * HH + lane]);
        accX = fmaf(w, v.x, accX);
        accY = fmaf(w, v.y, accY);
    }
}

// phase1: z1 = z0_own + c*(S.z0); z0_own recomputed from fp32 own h.
__device__ __forceinline__ void phase1_node(int n, int lane,
                                            const float* __restrict__ h,
                                            const unsigned short* __restrict__ z0bf8,
                                            unsigned short* __restrict__ z1bf8,
                                            const int* __restrict__ rp, const uint2* __restrict__ edges,
                                            float a, float b, float idx_, float idy_, float cx, float cy) {
    float accX = 0.f, accY = 0.f;
    gather_acc(z0bf8, edges, rp[n], rp[n + 1], lane, accX, accY);
    const float* hn = h + (size_t)n * 128;
    float hx = hn[lane], hy = hn[HH + lane];
    float xy = hx * hy;
    float z0x = (hx + DTC * (a * hx - b * xy)) * idx_;
    float z0y = (hy + DTC * (b * xy - a * hy)) * idy_;
    z1bf8[(size_t)n * HH + lane] = pack_fp8x2(fmaf(cx, accX, z0x), fmaf(cy, accY, z0y));
}

// phase2: z2 = z0_own + c*(S.z1); gate + LN; h in place; write next-layer z0.
__device__ __forceinline__ void phase2_node(int n, int lane,
                                            float* __restrict__ h,
                                            unsigned short* __restrict__ z0bf8,
                                            const unsigned short* __restrict__ z1bf8,
                                            const int* __restrict__ rp, const uint2* __restrict__ edges,
                                            float a, float b, float idx_, float idy_, float cx, float cy,
                                            float g, const float* __restrict__ lwr, const float* __restrict__ lbr,
                                            float a2, float b2, float idx2, float idy2, bool wz0) {
    float accX = 0.f, accY = 0.f;
    gather_acc(z1bf8, edges, rp[n], rp[n + 1], lane, accX, accY);
    float* hn = h + (size_t)n * 128;
    float hx = hn[lane], hy = hn[HH + lane];
    float xy = hx * hy;
    float z0x = (hx + DTC * (a * hx - b * xy)) * idx_;
    float z0y = (hy + DTC * (b * xy - a * hy)) * idy_;
    float z2x = fmaf(cx, accX, z0x);
    float z2y = fmaf(cy, accY, z0y);
    float nx = fmaf(g, z2x - hx, hx);
    float ny = fmaf(g, z2y - hy, hy);
    float s1 = nx + ny;
    float s2 = fmaf(nx, nx, ny * ny);
#pragma unroll
    for (int m = 1; m < 64; m <<= 1) {
        s1 += __shfl_xor(s1, m, 64);
        s2 += __shfl_xor(s2, m, 64);
    }
    float mean = s1 * (1.0f / 128.0f);
    float var = fmaf(-mean, mean, s2 * (1.0f / 128.0f));
    float rstd = rsqrtf(var + LNEPS);
    float ox = fmaf((nx - mean) * rstd, lwr[lane], lbr[lane]);
    float oy = fmaf((ny - mean) * rstd, lwr[HH + lane], lbr[HH + lane]);
    hn[lane] = ox;
    hn[HH + lane] = oy;
    if (wz0) {
        float xy2 = ox * oy;
        float r2x = ox + DTC * (a2 * ox - b2 * xy2);
        float r2y = oy + DTC * (b2 * xy2 - a2 * oy);
        z0bf8[(size_t)n * HH + lane] = pack_fp8x2(r2x * idx2, r2y * idy2);
    }
}

// ---------------- cooperative fused layer loop ----------------

__global__ __launch_bounds__(256, 4) void k_layers(
    float* __restrict__ h, unsigned short* __restrict__ z0bf8, unsigned short* __restrict__ z1bf8,
    const int* __restrict__ rp, const uint2* __restrict__ edges,
    const float* __restrict__ alpha, const float* __restrict__ beta,
    const float* __restrict__ dxp, const float* __restrict__ dyp,
    const float* __restrict__ taup, const float* __restrict__ lnw, const float* __restrict__ lnb) {
    cg::grid_group grid = cg::this_grid();
    int lane = threadIdx.x & 63;
    int gw = (int)((blockIdx.x * blockDim.x + threadIdx.x) >> 6);
    int nw = (int)((gridDim.x * blockDim.x) >> 6);
    for (int l = 0; l < NL; ++l) {
        float a = alpha[l], b = beta[l], dx = dxp[l], dy = dyp[l];
        float idx_ = 1.0f / (1.0f + DTC * dx);
        float idy_ = 1.0f / (1.0f + DTC * dy);
        float cx = DTC * dx * idx_, cy = DTC * dy * idy_;
        for (int n = gw; n < NN; n += nw)
            phase1_node(n, lane, h, z0bf8, z1bf8, rp, edges, a, b, idx_, idy_, cx, cy);
        grid.sync();
        int l2 = (l + 1 < NL) ? l + 1 : l;
        float a2 = alpha[l2], b2 = beta[l2];
        float idx2 = 1.0f / (1.0f + DTC * dxp[l2]);
        float idy2 = 1.0f / (1.0f + DTC * dyp[l2]);
        float g = 1.0f / (1.0f + expf(-taup[l]));
        bool wz0 = (l + 1 < NL);
        for (int n = gw; n < NN; n += nw)
            phase2_node(n, lane, h, z0bf8, z1bf8, rp, edges, a, b, idx_, idy_, cx, cy, g,
                        lnw + (size_t)l * 128, lnb + (size_t)l * 128, a2, b2, idx2, idy2, wz0);
        grid.sync();
    }
}

// ---------------- fallback per-phase kernels ----------------

__global__ __launch_bounds__(256) void k_phase1(const float* __restrict__ h,
                                                const unsigned short* __restrict__ z0bf8,
                                                unsigned short* __restrict__ z1bf8,
                                                const int* __restrict__ rp, const uint2* __restrict__ edges,
                                                const float* __restrict__ alpha, const float* __restrict__ beta,
                                                const float* __restrict__ dxp, const float* __restrict__ dyp,
                                                int l) {
    int lane = threadIdx.x & 63, wid = threadIdx.x >> 6;
    int n = blockIdx.x * 4 + wid;
    float a = alpha[l], b = beta[l], dx = dxp[l], dy = dyp[l];
    float idx_ = 1.0f / (1.0f + DTC * dx);
    float idy_ = 1.0f / (1.0f + DTC * dy);
    float cx = DTC * dx * idx_, cy = DTC * dy * idy_;
    phase1_node(n, lane, h, z0bf8, z1bf8, rp, edges, a, b, idx_, idy_, cx, cy);
}

__global__ __launch_bounds__(256) void k_phase2(float* __restrict__ h,
                                                unsigned short* __restrict__ z0bf8,
                                                const unsigned short* __restrict__ z1bf8,
                                                const int* __restrict__ rp, const uint2* __restrict__ edges,
                                                const float* __restrict__ alpha, const float* __restrict__ beta,
                                                const float* __restrict__ dxp, const float* __restrict__ dyp,
                                                const float* __restrict__ taup,
                                                const float* __restrict__ lnw, const float* __restrict__ lnb,
                                                int l) {
    int lane = threadIdx.x & 63, wid = threadIdx.x >> 6;
    int n = blockIdx.x * 4 + wid;
    float a = alpha[l], b = beta[l], dx = dxp[l], dy = dyp[l];
    float idx_ = 1.0f / (1.0f + DTC * dx);
    float idy_ = 1.0f / (1.0f + DTC * dy);
    float cx = DTC * dx * idx_, cy = DTC * dy * idy_;
    int l2 = (l + 1 < NL) ? l + 1 : l;
    float a2 = alpha[l2], b2 = beta[l2];
    float idx2 = 1.0f / (1.0f + DTC * dxp[l2]);
    float idy2 = 1.0f / (1.0f + DTC * dyp[l2]);
    float g = 1.0f / (1.0f + expf(-taup[l]));
    bool wz0 = (l + 1 < NL);
    phase2_node(n, lane, h, z0bf8, z1bf8, rp, edges, a, b, idx_, idy_, cx, cy, g,
                lnw + (size_t)l * 128, lnb + (size_t)l * 128, a2, b2, idx2, idy2, wz0);
}

// ---------------- output head ----------------

__global__ __launch_bounds__(256) void k_out(const float* __restrict__ h, const float* __restrict__ ow,
                                             const float* __restrict__ ob, const float* __restrict__ lsp,
                                             float* __restrict__ out) {
    __shared__ float hs[64][65];
    __shared__ float ows[NCLS][65];
    __shared__ float obs[NCLS];
    int t = threadIdx.x;
    int n0 = blockIdx.x * 64;
#pragma unroll
    for (int i = 0; i < 16; ++i) {
        int idx = i * 256 + t;
        int r = idx >> 6, c = idx & 63;
        int n = n0 + r;
        hs[r][c] = (n < NN) ? h[(size_t)n * 128 + c] : 0.f;
    }
#pragma unroll
    for (int i = 0; i < 10; ++i) {
        int idx = i * 256 + t;
        int j = idx >> 6, c = idx & 63;
        ows[j][c] = ow[j * HH + c];
    }
    if (t < NCLS) obs[t] = ob[t];
    __syncthreads();
    float ls = lsp[0];
#pragma unroll
    for (int i = 0; i < 10; ++i) {
        int o = i * 256 + t;
        int nl = o / NCLS;
        int j = o - nl * NCLS;
        float acc = 0.f;
#pragma unroll 8
        for (int k = 0; k < HH; ++k) acc = fmaf(hs[nl][k], ows[j][k], acc);
        int n = n0 + nl;
        if (n < NN) out[(size_t)n * NCLS + j] = fmaf(ls, acc, obs[j]);
    }
}

// ---------------- launcher ----------------

extern "C" void kernel_launch(void* const* d_in, const int* in_sizes, int n_in,
                              void* d_out, int out_size, void* d_ws, size_t ws_size,
                              hipStream_t stream) {
    const float* x     = (const float*)d_in[0];
    const int*   ei    = (const int*)d_in[1];
    const float* lw    = (const float*)d_in[2];
    const float* lb    = (const float*)d_in[3];
    const float* alpha = (const float*)d_in[4];
    const float* beta  = (const float*)d_in[5];
    const float* dxp   = (const float*)d_in[6];
    const float* dyp   = (const float*)d_in[7];
    const float* taup  = (const float*)d_in[8];
    const float* lnw   = (const float*)d_in[9];
    const float* lnb   = (const float*)d_in[10];
    const float* ow    = (const float*)d_in[11];
    const float* ob    = (const float*)d_in[12];
    const float* lsp   = (const float*)d_in[13];
    float* out = (float*)d_out;

    const int* srcp = ei;
    const int* dstp = ei + NE;

    char* ws = (char*)d_ws;
    size_t o = 0;
    auto alloc = [&](size_t b) { size_t r = o; o += (b + 255) & ~(size_t)255; return r; };
    int*            row_ptr = (int*)(ws + alloc((NN + 1) * sizeof(int)));
    int*            deg     = (int*)(ws + alloc(NN * sizeof(int)));
    int*            cnt     = (int*)(ws + alloc(NN * sizeof(int)));
    float*          dinv    = (float*)(ws + alloc(NN * sizeof(float)));
    int*            bsum    = (int*)(ws + alloc(256 * sizeof(int)));
    int*            boff    = (int*)(ws + alloc(256 * sizeof(int)));
    uint2*          edges   = (uint2*)(ws + alloc((size_t)NE * sizeof(uint2)));
    float*          hbuf    = (float*)(ws + alloc((size_t)NN * 128 * sizeof(float)));
    unsigned short* z0bf8   = (unsigned short*)(ws + alloc((size_t)NN * HH * sizeof(unsigned short)));
    unsigned short* z1bf8   = (unsigned short*)(ws + alloc((size_t)NN * HH * sizeof(unsigned short)));

    hipMemsetAsync(deg, 0, NN * sizeof(int), stream);
    hipMemsetAsync(cnt, 0, NN * sizeof(int), stream);

    k_deg<<<(NE + 255) / 256, 256, 0, stream>>>(dstp, deg);
    k_scan1<<<NB_SCAN, 256, 0, stream>>>(deg, row_ptr, bsum, dinv);
    k_scan2<<<1, 256, 0, stream>>>(bsum, boff);
    k_scan3<<<NB_SCAN, 256, 0, stream>>>(row_ptr, boff);
    k_scatter<<<(NE + 255) / 256, 256, 0, stream>>>(srcp, dstp, dinv, row_ptr, cnt, edges);

    k_lift<<<NN / LIFT_NPB, 256, 0, stream>>>(x, lw, lb, alpha, beta, dxp, dyp, hbuf, z0bf8);

    // fused cooperative layer loop; fall back to per-phase launches if unsupported
    {
        float* h_ = hbuf; unsigned short* z0_ = z0bf8; unsigned short* z1_ = z1bf8;
        const int* rp_ = row_ptr; const uint2* ed_ = edges;
        const float* al_ = alpha; const float* be_ = beta; const float* dx_ = dxp;
        const float* dy_ = dyp; const float* ta_ = taup; const float* lw_ = lnw; const float* lb_ = lnb;
        void* args[12] = { &h_, &z0_, &z1_, &rp_, &ed_, &al_, &be_, &dx_, &dy_, &ta_, &lw_, &lb_ };
        hipError_t cerr = hipLaunchCooperativeKernel((const void*)k_layers, dim3(COOP_BLOCKS), dim3(256),
                                                     args, 0, stream);
        if (cerr != hipSuccess) {
            for (int l = 0; l < NL; ++l) {
                k_phase1<<<NN / 4, 256, 0, stream>>>(hbuf, z0bf8, z1bf8, row_ptr, edges,
                                                     alpha, beta, dxp, dyp, l);
                k_phase2<<<NN / 4, 256, 0, stream>>>(hbuf, z0bf8, z1bf8, row_ptr, edges,
                                                     alpha, beta, dxp, dyp, taup, lnw, lnb, l);
            }
        }
    }

    k_out<<<(NN + 63) / 64, 256, 0, stream>>>(hbuf, ow, ob, lsp, out);
}

// Round 6
// 1303.818 us; speedup vs baseline: 4.2226x; 4.2226x over previous
//
#include <hip/hip_runtime.h>

#define NN 50000
#define NE 800000
#define CIN 128
#define HH 64
#define NCLS 40
#define NL 15
#define DTC 0.1f
#define LNEPS 1e-5f
#define NB_SCAN 196   // ceil(50000/256)

typedef float f32x2 __attribute__((ext_vector_type(2)));

// ---------------- bf16x2 / fp8x2 pack-unpack ----------------

__device__ inline unsigned pack_bf2(float x, float y) {
    unsigned ux = __float_as_uint(x);
    unsigned uy = __float_as_uint(y);
    ux = (ux + 0x7fffu + ((ux >> 16) & 1u)) >> 16;   // RNE
    uy = (uy + 0x7fffu + ((uy >> 16) & 1u)) >> 16;
    return ux | (uy << 16);
}
__device__ inline float2 unpack_bf2(unsigned p) {
    float2 r;
    r.x = __uint_as_float(p << 16);
    r.y = __uint_as_float(p & 0xffff0000u);
    return r;
}
__device__ inline unsigned short pack_fp8x2(float x, float y) {
    int r = __builtin_amdgcn_cvt_pk_fp8_f32(x, y, 0, false);
    return (unsigned short)(r & 0xffff);
}
__device__ inline float2 unpack_fp8x2(unsigned short p) {
    f32x2 v = __builtin_amdgcn_cvt_pk_f32_fp8((int)(unsigned)p, false);
    float2 r; r.x = v.x; r.y = v.y; return r;
}

// ---------------- degree / normalization precompute ----------------

__global__ __launch_bounds__(256) void k_deg(const int* __restrict__ dst, int* __restrict__ deg) {
    int e = blockIdx.x * 256 + threadIdx.x;
    if (e < NE) atomicAdd(&deg[dst[e]], 1);
}

__global__ __launch_bounds__(256) void k_scan1(const int* __restrict__ deg, int* __restrict__ rp,
                                               int* __restrict__ bsum, float* __restrict__ dinv) {
    int i = blockIdx.x * 256 + threadIdx.x;
    int v = (i < NN) ? deg[i] : 0;
    if (i < NN) dinv[i] = rsqrtf(fmaxf((float)v, 1.0f));
    int lane = threadIdx.x & 63, wid = threadIdx.x >> 6;
    int inc = v;
#pragma unroll
    for (int d = 1; d < 64; d <<= 1) {
        int t = __shfl_up(inc, d, 64);
        if (lane >= d) inc += t;
    }
    __shared__ int wsum[4];
    if (lane == 63) wsum[wid] = inc;
    __syncthreads();
    int woff = 0;
#pragma unroll
    for (int w = 0; w < 4; ++w)
        if (w < wid) woff += wsum[w];
    if (i < NN) rp[i] = woff + inc - v;
    if (threadIdx.x == 255) bsum[blockIdx.x] = woff + inc;
}

__global__ __launch_bounds__(256) void k_scan2(const int* __restrict__ bsum, int* __restrict__ boff) {
    int t = threadIdx.x;
    int v = (t < NB_SCAN) ? bsum[t] : 0;
    int lane = t & 63, wid = t >> 6;
    int inc = v;
#pragma unroll
    for (int d = 1; d < 64; d <<= 1) {
        int tt = __shfl_up(inc, d, 64);
        if (lane >= d) inc += tt;
    }
    __shared__ int wsum[4];
    if (lane == 63) wsum[wid] = inc;
    __syncthreads();
    int woff = 0;
#pragma unroll
    for (int w = 0; w < 4; ++w)
        if (w < wid) woff += wsum[w];
    boff[t] = woff + inc - v;
}

__global__ __launch_bounds__(256) void k_scan3(int* __restrict__ rp, const int* __restrict__ boff) {
    int i = blockIdx.x * 256 + threadIdx.x;
    if (i < NN) rp[i] += boff[i >> 8];
    else if (i == NN) rp[NN] = NE;
}

// edge record: {src*128 byte-offset into fp8 row buffers, ewt bits} -> one 8B store
__global__ __launch_bounds__(256) void k_scatter(const int* __restrict__ src, const int* __restrict__ dst,
                                                 const float* __restrict__ dinv, const int* __restrict__ rp,
                                                 int* __restrict__ cnt, uint2* __restrict__ edges) {
    int e = blockIdx.x * 256 + threadIdx.x;
    if (e >= NE) return;
    int s = src[e], d = dst[e];
    int pos = rp[d] + atomicAdd(&cnt[d], 1);
    uint2 rec;
    rec.x = (unsigned)s * 128u;           // byte offset of row s (64 ch * 2B)
    rec.y = __float_as_uint(dinv[s] * dinv[d]);
    edges[pos] = rec;
}

// ---------------- lift: h = [tanh(x @ lift_w^T + b), ones]; writes layer-0 z0 ----

#define LIFT_NPB 16

__global__ __launch_bounds__(256) void k_lift(const float* __restrict__ x, const float* __restrict__ lw,
                                              const float* __restrict__ lb,
                                              const float* __restrict__ alpha, const float* __restrict__ beta,
                                              const float* __restrict__ dxp, const float* __restrict__ dyp,
                                              float* __restrict__ h, unsigned short* __restrict__ z0bf8) {
    __shared__ unsigned Wt2[CIN / 2][HH + 1];
    __shared__ float xs[LIFT_NPB][CIN];
    int t = threadIdx.x;
    for (int idx = t; idx < (CIN / 2) * HH; idx += 256) {
        int c = idx & 63, kk = idx >> 6;
        Wt2[kk][c] = pack_bf2(lw[c * CIN + 2 * kk], lw[c * CIN + 2 * kk + 1]);
    }
    int n0 = blockIdx.x * LIFT_NPB;
#pragma unroll
    for (int i = 0; i < LIFT_NPB * CIN / 256; ++i) {
        int idx = i * 256 + t;
        int r = idx >> 7, c = idx & 127;
        xs[r][c] = x[(size_t)(n0 + r) * CIN + c];
    }
    __syncthreads();
    int lane = t & 63, wid = t >> 6;
    float bias = lb[lane];
    float a = alpha[0], b = beta[0];
    float idx0 = 1.0f / (1.0f + DTC * dxp[0]);
    float idy0 = 1.0f / (1.0f + DTC * dyp[0]);
#pragma unroll
    for (int i = 0; i < 4; ++i) {
        int nl = wid * 4 + i;
        float acc0 = 0.f, acc1 = 0.f;
        const float2* xr = (const float2*)&xs[nl][0];
#pragma unroll 8
        for (int kk = 0; kk < CIN / 2; ++kk) {
            float2 xv = xr[kk];
            float2 wv = unpack_bf2(Wt2[kk][lane]);
            acc0 = fmaf(xv.x, wv.x, acc0);
            acc1 = fmaf(xv.y, wv.y, acc1);
        }
        float hx = tanhf(bias + acc0 + acc1);
        int n = n0 + nl;
        float* hr = h + (size_t)n * 128;
        hr[lane] = hx;
        hr[HH + lane] = 1.0f;
        // layer-0 z0 = rhs/diag with (X,Y)=(hx,1): xy = hx
        float rx = hx + DTC * (a * hx - b * hx);
        float ry = 1.0f + DTC * (b * hx - a);
        z0bf8[(size_t)n * HH + lane] = pack_fp8x2(rx * idx0, ry * idy0);
    }
}

// ---------------- gather core ----------------

__device__ __forceinline__ void gather_acc(const unsigned short* __restrict__ srcbuf,
                                           const uint2* __restrict__ edges,
                                           int e0, int e1, int lane2, float& accX, float& accY) {
    const char* base = (const char*)srcbuf;
    int e = e0;
    for (; e + 8 <= e1; e += 8) {
        uint2 ed[8]; unsigned short g[8];
#pragma unroll
        for (int u = 0; u < 8; ++u) ed[u] = edges[e + u];
#pragma unroll
        for (int u = 0; u < 8; ++u) g[u] = *(const unsigned short*)(base + ed[u].x + lane2);
#pragma unroll
        for (int u = 0; u < 8; ++u) {
            float w = __uint_as_float(ed[u].y);
            float2 v = unpack_fp8x2(g[u]);
            accX = fmaf(w, v.x, accX);
            accY = fmaf(w, v.y, accY);
        }
    }
    for (; e < e1; ++e) {
        uint2 ed = edges[e];
        float w = __uint_as_float(ed.y);
        float2 v = unpack_fp8x2(*(const unsigned short*)(base + ed.x + lane2));
        accX = fmaf(w, v.x, accX);
        accY = fmaf(w, v.y, accY);
    }
}

// ---------------- phase kernels ----------------
// phase1: z1 = z0_own(fp8) + c*(S.z0) — no fp32 h access at all.

__global__ __launch_bounds__(256) void k_phase1(const unsigned short* __restrict__ z0bf8,
                                                unsigned short* __restrict__ z1bf8,
                                                const int* __restrict__ rp, const uint2* __restrict__ edges,
                                                const float* __restrict__ dxp, const float* __restrict__ dyp,
                                                int l) {
    int lane = threadIdx.x & 63, wid = threadIdx.x >> 6;
    int n = blockIdx.x * 4 + wid;
    float dx = dxp[l], dy = dyp[l];
    float cx = DTC * dx / (1.0f + DTC * dx);
    float cy = DTC * dy / (1.0f + DTC * dy);
    float accX = 0.f, accY = 0.f;
    gather_acc(z0bf8, edges, rp[n], rp[n + 1], lane * 2, accX, accY);
    float2 z0 = unpack_fp8x2(z0bf8[(size_t)n * HH + lane]);
    z1bf8[(size_t)n * HH + lane] = pack_fp8x2(fmaf(cx, accX, z0.x), fmaf(cy, accY, z0.y));
}

// phase2: z2 = z0_own(fp32, recomputed) + c*(S.z1); gate + LN; h in place; next-layer z0.

__global__ __launch_bounds__(256) void k_phase2(float* __restrict__ h,
                                                unsigned short* __restrict__ z0bf8,
                                                const unsigned short* __restrict__ z1bf8,
                                                const int* __restrict__ rp, const uint2* __restrict__ edges,
                                                const float* __restrict__ alpha, const float* __restrict__ beta,
                                                const float* __restrict__ dxp, const float* __restrict__ dyp,
                                                const float* __restrict__ taup,
                                                const float* __restrict__ lnw, const float* __restrict__ lnb,
                                                int l) {
    int lane = threadIdx.x & 63, wid = threadIdx.x >> 6;
    int n = blockIdx.x * 4 + wid;
    float a = alpha[l], b = beta[l], dx = dxp[l], dy = dyp[l];
    float idx_ = 1.0f / (1.0f + DTC * dx);
    float idy_ = 1.0f / (1.0f + DTC * dy);
    float cx = DTC * dx * idx_, cy = DTC * dy * idy_;
    float accX = 0.f, accY = 0.f;
    gather_acc(z1bf8, edges, rp[n], rp[n + 1], lane * 2, accX, accY);
    float* hn = h + (size_t)n * 128;
    float hx = hn[lane], hy = hn[HH + lane];
    float xy = hx * hy;
    float z0x = (hx + DTC * (a * hx - b * xy)) * idx_;
    float z0y = (hy + DTC * (b * xy - a * hy)) * idy_;
    float z2x = fmaf(cx, accX, z0x);
    float z2y = fmaf(cy, accY, z0y);
    float g = 1.0f / (1.0f + expf(-taup[l]));
    float nx = fmaf(g, z2x - hx, hx);
    float ny = fmaf(g, z2y - hy, hy);
    float s1 = nx + ny;
    float s2 = fmaf(nx, nx, ny * ny);
#pragma unroll
    for (int m = 1; m < 64; m <<= 1) {
        s1 += __shfl_xor(s1, m, 64);
        s2 += __shfl_xor(s2, m, 64);
    }
    float mean = s1 * (1.0f / 128.0f);
    float var = fmaf(-mean, mean, s2 * (1.0f / 128.0f));
    float rstd = rsqrtf(var + LNEPS);
    float ox = fmaf((nx - mean) * rstd, lnw[(size_t)l * 128 + lane], lnb[(size_t)l * 128 + lane]);
    float oy = fmaf((ny - mean) * rstd, lnw[(size_t)l * 128 + HH + lane], lnb[(size_t)l * 128 + HH + lane]);
    hn[lane] = ox;
    hn[HH + lane] = oy;
    if (l + 1 < NL) {
        float a2 = alpha[l + 1], b2 = beta[l + 1];
        float idx2 = 1.0f / (1.0f + DTC * dxp[l + 1]);
        float idy2 = 1.0f / (1.0f + DTC * dyp[l + 1]);
        float xy2 = ox * oy;
        float r2x = ox + DTC * (a2 * ox - b2 * xy2);
        float r2y = oy + DTC * (b2 * xy2 - a2 * oy);
        z0bf8[(size_t)n * HH + lane] = pack_fp8x2(r2x * idx2, r2y * idy2);
    }
}

// ---------------- output head ----------------

__global__ __launch_bounds__(256) void k_out(const float* __restrict__ h, const float* __restrict__ ow,
                                             const float* __restrict__ ob, const float* __restrict__ lsp,
                                             float* __restrict__ out) {
    __shared__ float hs[64][65];
    __shared__ float ows[NCLS][65];
    __shared__ float obs[NCLS];
    int t = threadIdx.x;
    int n0 = blockIdx.x * 64;
#pragma unroll
    for (int i = 0; i < 16; ++i) {
        int idx = i * 256 + t;
        int r = idx >> 6, c = idx & 63;
        int n = n0 + r;
        hs[r][c] = (n < NN) ? h[(size_t)n * 128 + c] : 0.f;
    }
#pragma unroll
    for (int i = 0; i < 10; ++i) {
        int idx = i * 256 + t;
        int j = idx >> 6, c = idx & 63;
        ows[j][c] = ow[j * HH + c];
    }
    if (t < NCLS) obs[t] = ob[t];
    __syncthreads();
    float ls = lsp[0];
#pragma unroll
    for (int i = 0; i < 10; ++i) {
        int o = i * 256 + t;
        int nl = o / NCLS;
        int j = o - nl * NCLS;
        float acc = 0.f;
#pragma unroll 8
        for (int k = 0; k < HH; ++k) acc = fmaf(hs[nl][k], ows[j][k], acc);
        int n = n0 + nl;
        if (n < NN) out[(size_t)n * NCLS + j] = fmaf(ls, acc, obs[j]);
    }
}

// ---------------- launcher ----------------

extern "C" void kernel_launch(void* const* d_in, const int* in_sizes, int n_in,
                              void* d_out, int out_size, void* d_ws, size_t ws_size,
                              hipStream_t stream) {
    const float* x     = (const float*)d_in[0];
    const int*   ei    = (const int*)d_in[1];
    const float* lw    = (const float*)d_in[2];
    const float* lb    = (const float*)d_in[3];
    const float* alpha = (const float*)d_in[4];
    const float* beta  = (const float*)d_in[5];
    const float* dxp   = (const float*)d_in[6];
    const float* dyp   = (const float*)d_in[7];
    const float* taup  = (const float*)d_in[8];
    const float* lnw   = (const float*)d_in[9];
    const float* lnb   = (const float*)d_in[10];
    const float* ow    = (const float*)d_in[11];
    const float* ob    = (const float*)d_in[12];
    const float* lsp   = (const float*)d_in[13];
    float* out = (float*)d_out;

    const int* srcp = ei;
    const int* dstp = ei + NE;

    char* ws = (char*)d_ws;
    size_t o = 0;
    auto alloc = [&](size_t b) { size_t r = o; o += (b + 255) & ~(size_t)255; return r; };
    int*            row_ptr = (int*)(ws + alloc((NN + 1) * sizeof(int)));
    int*            deg     = (int*)(ws + alloc(NN * sizeof(int)));
    int*            cnt     = (int*)(ws + alloc(NN * sizeof(int)));
    float*          dinv    = (float*)(ws + alloc(NN * sizeof(float)));
    int*            bsum    = (int*)(ws + alloc(256 * sizeof(int)));
    int*            boff    = (int*)(ws + alloc(256 * sizeof(int)));
    uint2*          edges   = (uint2*)(ws + alloc((size_t)NE * sizeof(uint2)));
    float*          hbuf    = (float*)(ws + alloc((size_t)NN * 128 * sizeof(float)));
    unsigned short* z0bf8   = (unsigned short*)(ws + alloc((size_t)NN * HH * sizeof(unsigned short)));
    unsigned short* z1bf8   = (unsigned short*)(ws + alloc((size_t)NN * HH * sizeof(unsigned short)));

    hipMemsetAsync(deg, 0, NN * sizeof(int), stream);
    hipMemsetAsync(cnt, 0, NN * sizeof(int), stream);

    k_deg<<<(NE + 255) / 256, 256, 0, stream>>>(dstp, deg);
    k_scan1<<<NB_SCAN, 256, 0, stream>>>(deg, row_ptr, bsum, dinv);
    k_scan2<<<1, 256, 0, stream>>>(bsum, boff);
    k_scan3<<<NB_SCAN, 256, 0, stream>>>(row_ptr, boff);
    k_scatter<<<(NE + 255) / 256, 256, 0, stream>>>(srcp, dstp, dinv, row_ptr, cnt, edges);

    k_lift<<<NN / LIFT_NPB, 256, 0, stream>>>(x, lw, lb, alpha, beta, dxp, dyp, hbuf, z0bf8);

    for (int l = 0; l < NL; ++l) {
        k_phase1<<<NN / 4, 256, 0, stream>>>(z0bf8, z1bf8, row_ptr, edges, dxp, dyp, l);
        k_phase2<<<NN / 4, 256, 0, stream>>>(hbuf, z0bf8, z1bf8, row_ptr, edges,
                                             alpha, beta, dxp, dyp, taup, lnw, lnb, l);
    }

    k_out<<<(NN + 63) / 64, 256, 0, stream>>>(hbuf, ow, ob, lsp, out);
}